// Round 11
// baseline (532.182 us; speedup 1.0000x reference)
//
#include <hip/hip_runtime.h>
#include <hip/hip_bf16.h>

// ===========================================================================
// EEGRCformer forward on MI355X. ALL tensors float32.
// R13: feat stage B remapped j-major: thread = (kpg=tid/40, j=tid%40), 240
// active; x chunk held in registers (rolling 5x float2) and reused across
// the thread's 4 kp values (kp = kpg+6u). Stage-B LDS reads 23000 -> 6000
// float2/block; inner loop 40 fma per 10 wave-uniform basis loads. Per-
// accumulator fma order unchanged -> bitwise-identical Cb.
// Everything else = R12 (former k-split x4, dist/fps/proj/finalize, no
// contended atomics).
// ws layout (floats): feats[128*62*504] | pf[128*62*128] (aliased as dmg
// before proj) | gsums[15] | gcnt[5] | assign[62 ints] | basis[23*50*4] |
// pbuf[128*20]
// ===========================================================================

typedef unsigned int u32;

#define N_SIG   7936          // 128*62
#define FDIM    504           // 36*14
#define DM      128

__device__ __constant__ int   bstart_c[7] = {1,4,8,12,16,20,30};
__device__ __constant__ int   bcnt_c[7]   = {3,4,4,4,4,10,15};
__device__ __constant__ float bandcnt_c[7] = {3.f,4.f,4.f,4.f,4.f,10.f,15.f};

// twiddles T[m] = e^{-i 2 pi m / 5} = (cos, -sin)
__device__ __constant__ float twr_c[5] = {
    1.0f, 0.30901699437494745f, -0.8090169943749475f,
    -0.8090169943749475f, 0.30901699437494745f};
__device__ __constant__ float twi_c[5] = {
    0.0f, -0.9510565162951535f, -0.5877852522924731f,
    0.5877852522924731f, 0.9510565162951535f};

// block reduce of (a,b) over 128 threads (2 waves); scr must be >=4 floats
static __device__ __forceinline__ void bred2(float& a, float& b, volatile float* scr, int tid){
    #pragma unroll
    for (int off = 32; off > 0; off >>= 1){
        a += __shfl_down(a, off, 64);
        b += __shfl_down(b, off, 64);
    }
    if ((tid & 63) == 0){ scr[tid>>6] = a; scr[2 + (tid>>6)] = b; }
    __syncthreads();
    a = scr[0] + scr[1];
    b = scr[2] + scr[3];
    __syncthreads();
}

// wide-block variant: only tid<128 contribute (identical tree to bred2);
// ALL threads must call it (contains barriers); result broadcast to all.
static __device__ __forceinline__ void bred2h(float& a, float& b, volatile float* scr, int tid){
    #pragma unroll
    for (int off = 32; off > 0; off >>= 1){
        a += __shfl_down(a, off, 64);
        b += __shfl_down(b, off, 64);
    }
    if (tid < 128 && (tid & 63) == 0){ scr[tid>>6] = a; scr[2 + (tid>>6)] = b; }
    __syncthreads();
    a = scr[0] + scr[1];
    b = scr[2] + scr[3];
    __syncthreads();
}

// 5-chunk combine of rect-DFT bin kk for window w (reads chunk DFTs in Cb).
static __device__ __forceinline__ float2 combine5(const float* __restrict__ Cb,
                                                  int w, int kk){
    const int k5 = kk % 5;
    const float* cb = Cb + ((size_t)(w*46 + kk))*2;
    float2 cv[5];
    #pragma unroll
    for (int c = 0; c < 5; ++c) cv[c] = *(const float2*)(cb + c*92);
    float ar = 0.f, ai = 0.f;
    int m = 0;
    #pragma unroll
    for (int c = 0; c < 5; ++c){
        float tr = twr_c[m], ti = twi_c[m];
        ar = fmaf(tr, cv[c].x, ar); ar = fmaf(-ti, cv[c].y, ar);
        ai = fmaf(tr, cv[c].y, ai); ai = fmaf(ti, cv[c].x, ai);
        m += k5; if (m >= 5) m -= 5;
    }
    float2 o; o.x = ar; o.y = ai;
    return o;
}

// ---------------------------------------------------------------------------
// Kernel 0: precompute chunk-DFT basis -> global.
// ---------------------------------------------------------------------------
__global__ __launch_bounds__(256) void basis_kernel(float* __restrict__ basis)
{
    int idx = blockIdx.x*256 + threadIdx.x;      // over 23*50 = 1150
    if (idx >= 1150) return;
    int kp = idx / 50;
    int n  = idx - kp*50;
    const float TPO = 0.025132741228718345f;     // 2*pi/250
    int k0 = 2*kp, k1 = 2*kp + 1;
    float s0, c0, s1, c1;
    sincosf((float)((k0*n) % 250) * TPO, &s0, &c0);
    sincosf((float)((k1*n) % 250) * TPO, &s1, &c1);
    float4 v; v.x = c0; v.y = -s0; v.z = c1; v.w = -s1;
    ((float4*)basis)[idx] = v;
}

// ---------------------------------------------------------------------------
// Kernel A: chunk DFTs -> window combine (Xw packed into Cb) -> Hann+PSD+DE
// -> z-norm -> feats. N_SIG blocks x 256 threads, 1 signal/block.
// LDS = 22.8 KB -> 7 blocks/CU.
// ---------------------------------------------------------------------------
__global__ __launch_bounds__(256) void feat_kernel(
        const float* __restrict__ x, const float* __restrict__ basis,
        float* __restrict__ feats)
{
    __shared__ __align__(16) float xs[2000];        //  8000 B
    __shared__ __align__(16) float Cb[3680];        // 14720 B chunk DFTs / Xw
    __shared__ float scr[16];

    const int tid = threadIdx.x;
    const int sig = blockIdx.x;

    // ---- stage A: stage x (coalesced float4) ----
    {
        const float4* xg = (const float4*)(x + (size_t)sig*2000);
        for (int i = tid; i < 500; i += 256) ((float4*)xs)[i] = xg[i];
    }
    __syncthreads();

    // ---- stage B: chunk DFTs, j-major. thread = (kpg=tid/40, j=tid%40),
    //      240 active; x chunk in registers, reused across kp = kpg+6u.
    if (tid < 240){
        const int kpg = tid / 40;
        const int j   = tid - kpg*40;
        const float2* xp = (const float2*)(xs + 50*j);     // 50j even -> aligned
        float acc[4][4];   // [u][cr0,ci0,cr1,ci1]
        #pragma unroll
        for (int u = 0; u < 4; ++u){
            acc[u][0]=0.f; acc[u][1]=0.f; acc[u][2]=0.f; acc[u][3]=0.f;
        }
        #pragma unroll
        for (int g = 0; g < 5; ++g){
            float2 xr[5];
            #pragma unroll
            for (int t5 = 0; t5 < 5; ++t5) xr[t5] = xp[g*5 + t5];
            #pragma unroll
            for (int u = 0; u < 4; ++u){
                const int kp = kpg + 6*u;
                if (kp < 23){
                    const float4* bp = ((const float4*)basis) + kp*50;
                    #pragma unroll
                    for (int t5 = 0; t5 < 5; ++t5){
                        const int t = g*5 + t5;
                        float2 xv = xr[t5];
                        float4 b0 = bp[2*t], b1 = bp[2*t+1];
                        acc[u][0] = fmaf(xv.x, b0.x, acc[u][0]);
                        acc[u][1] = fmaf(xv.x, b0.y, acc[u][1]);
                        acc[u][2] = fmaf(xv.x, b0.z, acc[u][2]);
                        acc[u][3] = fmaf(xv.x, b0.w, acc[u][3]);
                        acc[u][0] = fmaf(xv.y, b1.x, acc[u][0]);
                        acc[u][1] = fmaf(xv.y, b1.y, acc[u][1]);
                        acc[u][2] = fmaf(xv.y, b1.z, acc[u][2]);
                        acc[u][3] = fmaf(xv.y, b1.w, acc[u][3]);
                    }
                }
            }
        }
        #pragma unroll
        for (int u = 0; u < 4; ++u){
            const int kp = kpg + 6*u;
            if (kp < 23){
                float4 o; o.x = acc[u][0]; o.y = acc[u][1]; o.z = acc[u][2]; o.w = acc[u][3];
                *(float4*)(Cb + ((size_t)(j*46 + 2*kp))*2) = o;
            }
        }
    }
    __syncthreads();   // Cb ready

    // ---- stage C1: windows 18..35 computed; write into slots 22..39 merged
    //      with compute of windows 0..17 (disjoint chunk reads); write 0..17.
    {
        const int i0 = tid, i1 = tid + 256, i2 = tid + 512, i3 = tid + 768;
        float2 r0, r1, r2, r3;
        { int w = 18 + i0/46, k = i0 - (i0/46)*46; r0 = combine5(Cb, w, k); }
        { int w = 18 + i1/46, k = i1 - (i1/46)*46; r1 = combine5(Cb, w, k); }
        { int w = 18 + i2/46, k = i2 - (i2/46)*46; r2 = combine5(Cb, w, k); }
        if (i3 < 828){ int w = 18 + i3/46, k = i3 - (i3/46)*46; r3 = combine5(Cb, w, k); }
        __syncthreads();   // all reads of chunks 22..39 complete
        { int w = 18 + i0/46, k = i0 - (i0/46)*46; *(float2*)(Cb + (w+4)*92 + 2*k) = r0; }
        { int w = 18 + i1/46, k = i1 - (i1/46)*46; *(float2*)(Cb + (w+4)*92 + 2*k) = r1; }
        { int w = 18 + i2/46, k = i2 - (i2/46)*46; *(float2*)(Cb + (w+4)*92 + 2*k) = r2; }
        if (i3 < 828){ int w = 18 + i3/46, k = i3 - (i3/46)*46; *(float2*)(Cb + (w+4)*92 + 2*k) = r3; }
        float2 s0, s1, s2, s3;
        { int w = i0/46, k = i0 - (i0/46)*46; s0 = combine5(Cb, w, k); }
        { int w = i1/46, k = i1 - (i1/46)*46; s1 = combine5(Cb, w, k); }
        { int w = i2/46, k = i2 - (i2/46)*46; s2 = combine5(Cb, w, k); }
        if (i3 < 828){ int w = i3/46, k = i3 - (i3/46)*46; s3 = combine5(Cb, w, k); }
        __syncthreads();   // low-window reads done
        { int w = i0/46, k = i0 - (i0/46)*46; *(float2*)(Cb + w*92 + 2*k) = s0; }
        { int w = i1/46, k = i1 - (i1/46)*46; *(float2*)(Cb + w*92 + 2*k) = s1; }
        { int w = i2/46, k = i2 - (i2/46)*46; *(float2*)(Cb + w*92 + 2*k) = s2; }
        if (i3 < 828){ int w = i3/46, k = i3 - (i3/46)*46; *(float2*)(Cb + w*92 + 2*k) = s3; }
    }
    __syncthreads();   // Xw fully materialized inside Cb

    // ---- stage C2+D: per-(window,band) Hann+PSD+DE, then block z-norm ----
    float psd = 0.f, de = 0.f;
    float s1p = 0.f, s2p = 0.f, s1d = 0.f, s2d = 0.f;
    int w = 0, bi = 0;
    if (tid < 252){
        w  = tid / 7;
        bi = tid - w*7;
        const int st = bstart_c[bi], cn = bcnt_c[bi];
        const float2* Xrow = (const float2*)(Cb + ((w < 18) ? w*92 : (w+4)*92));
        float2 xm = Xrow[st-1], xc = Xrow[st];
        float p = 0.f;
        for (int q = 0; q < cn; ++q){
            float2 xp = Xrow[st+q+1];
            float Hr = 0.5f*xc.x - 0.25f*(xm.x + xp.x);
            float Hi = 0.5f*xc.y - 0.25f*(xm.y + xp.y);
            p = fmaf(Hr, Hr, p); p = fmaf(Hi, Hi, p);
            xm = xc; xc = xp;
        }
        psd = p * (1.0f/250.0f) / bandcnt_c[bi];
        de  = 0.5f * logf(17.079468445347134f*psd + 1e-9f);
        s1p = psd; s2p = psd*psd; s1d = de; s2d = de*de;
    }
    // block reduce 4 sums over 256 threads (4 waves)
    #pragma unroll
    for (int off = 32; off > 0; off >>= 1){
        s1p += __shfl_down(s1p, off, 64); s2p += __shfl_down(s2p, off, 64);
        s1d += __shfl_down(s1d, off, 64); s2d += __shfl_down(s2d, off, 64);
    }
    {
        const int wid = tid >> 6;
        if ((tid & 63) == 0){
            scr[0*4 + wid] = s1p; scr[1*4 + wid] = s2p;
            scr[2*4 + wid] = s1d; scr[3*4 + wid] = s2d;
        }
    }
    __syncthreads();
    s1p = scr[0] + scr[1] + scr[2]  + scr[3];
    s2p = scr[4] + scr[5] + scr[6]  + scr[7];
    s1d = scr[8] + scr[9] + scr[10] + scr[11];
    s2d = scr[12] + scr[13] + scr[14] + scr[15];

    if (tid < 252){
        float mp = s1p / 252.f;
        float vp = fmaxf((s2p - 252.f*mp*mp) / 251.f, 0.f);
        float sp = sqrtf(vp) + 1e-9f;
        float md = s1d / 252.f;
        float vd = fmaxf((s2d - 252.f*md*md) / 251.f, 0.f);
        float sd = sqrtf(vd) + 1e-9f;
        float* ob = feats + (size_t)sig * FDIM;
        ob[w*14 + bi]     = (psd - mp) / sp;
        ob[w*14 + 7 + bi] = (de  - md) / sd;
    }
}

// ---------------------------------------------------------------------------
// Kernel B1: 62x62 feature distance matrix -> global dmg. (R9 version.)
// ---------------------------------------------------------------------------
__global__ __launch_bounds__(512) void dist_kernel(
        const float* __restrict__ feats, float* __restrict__ dmg)
{
    __shared__ float Fc[62*130];     // 32.2 KB

    const int tid = threadIdx.x;
    const int b   = blockIdx.x >> 1;
    const int h   = blockIdx.x & 1;
    const int nt  = h ? 465 : 496;

    int ti = 0, tj = 0;
    const bool act = tid < nt;
    if (act){ ti = (h ? 16 : 0) + tid/31; tj = tid - (tid/31)*31; }

    float a00 = 0.f, a01 = 0.f, a10 = 0.f, a11 = 0.f;

    for (int ch = 0; ch < 4; ++ch){
        if (ch) __syncthreads();
        for (int i = tid; i < 62*63; i += 512){
            int r = i / 63, dc2 = i - r*63;
            *(float2*)(Fc + r*130 + 2*dc2) =
                *(const float2*)(feats + ((size_t)b*62 + r)*FDIM + ch*126 + 2*dc2);
        }
        __syncthreads();
        if (act){
            const float2* ri0 = (const float2*)(Fc + (2*ti)*130);
            const float2* ri1 = (const float2*)(Fc + (2*ti+1)*130);
            const float2* rj0 = (const float2*)(Fc + (2*tj)*130);
            const float2* rj1 = (const float2*)(Fc + (2*tj+1)*130);
            for (int g = 0; g < 9; ++g){      // 9 x 7 = 63
                const int q0 = g*7;
                float2 A0[7], A1[7], C0[7], C1[7];
                #pragma unroll
                for (int u = 0; u < 7; ++u){
                    A0[u] = ri0[q0+u]; A1[u] = ri1[q0+u];
                    C0[u] = rj0[q0+u]; C1[u] = rj1[q0+u];
                }
                #pragma unroll
                for (int u = 0; u < 7; ++u){
                    float d;
                    d = A0[u].x-C0[u].x; a00 = fmaf(d,d,a00); d = A0[u].y-C0[u].y; a00 = fmaf(d,d,a00);
                    d = A0[u].x-C1[u].x; a01 = fmaf(d,d,a01); d = A0[u].y-C1[u].y; a01 = fmaf(d,d,a01);
                    d = A1[u].x-C0[u].x; a10 = fmaf(d,d,a10); d = A1[u].y-C0[u].y; a10 = fmaf(d,d,a10);
                    d = A1[u].x-C1[u].x; a11 = fmaf(d,d,a11); d = A1[u].y-C1[u].y; a11 = fmaf(d,d,a11);
                }
            }
        }
    }
    if (act){
        float* dst = dmg + (size_t)b*3844;
        dst[(2*ti)*62   + 2*tj]   = sqrtf(a00);
        dst[(2*ti)*62   + 2*tj+1] = sqrtf(a01);
        dst[(2*ti+1)*62 + 2*tj]   = sqrtf(a10);
        dst[(2*ti+1)*62 + 2*tj+1] = sqrtf(a11);
    }
}

// ---------------------------------------------------------------------------
// Kernel B2: per-batch FPS(5) -> temp assign -> per-block reduction -> pbuf.
// 128 blocks x 64 threads. No contended atomics.
// ---------------------------------------------------------------------------
__global__ __launch_bounds__(64) void fps_kernel(
        const float* __restrict__ dmg, const float* __restrict__ pos_emb,
        float* __restrict__ pbuf)
{
    __shared__ float Dm[3844];
    __shared__ float mdv[62];
    __shared__ float rsv[62];
    __shared__ int   seli[5];
    __shared__ float ccen[5][3];
    __shared__ int   sbest[62];
    __shared__ float sp3[62][3];

    const int tid = threadIdx.x;
    const int b   = blockIdx.x;

    {
        const float4* src = (const float4*)(dmg + (size_t)b*3844);
        for (int i = tid; i < 961; i += 64) ((float4*)Dm)[i] = src[i];
    }
    __syncthreads();

    if (tid < 62){ float s = 0.f; for (int j = 0; j < 62; ++j) s += Dm[tid*62 + j]; rsv[tid] = s; }
    __syncthreads();
    if (tid == 0){
        int bi = 0; float bv = rsv[0];
        for (int i = 1; i < 62; ++i) if (rsv[i] > bv){ bv = rsv[i]; bi = i; }
        seli[0] = bi;
    }
    __syncthreads();
    if (tid < 62) mdv[tid] = Dm[seli[0]*62 + tid];
    __syncthreads();
    for (int it = 1; it < 5; ++it){
        if (tid == 0){
            int bi = 0; float bv = mdv[0];
            for (int i = 1; i < 62; ++i) if (mdv[i] > bv){ bv = mdv[i]; bi = i; }
            seli[it] = bi;
        }
        __syncthreads();
        if (tid < 62) mdv[tid] = fminf(mdv[tid], Dm[seli[it]*62 + tid]);
        __syncthreads();
    }
    if (tid < 5){
        int c0 = seli[tid];
        #pragma unroll
        for (int j = 0; j < 3; ++j) ccen[tid][j] = pos_emb[((size_t)b*62 + c0)*3 + j];
    }
    __syncthreads();
    if (tid < 62){
        float px = pos_emb[((size_t)b*62 + tid)*3 + 0];
        float py = pos_emb[((size_t)b*62 + tid)*3 + 1];
        float pz = pos_emb[((size_t)b*62 + tid)*3 + 2];
        int best = 0; float bd = 3.4e38f;
        #pragma unroll
        for (int t = 0; t < 5; ++t){
            float dx = px - ccen[t][0], dy = py - ccen[t][1], dz = pz - ccen[t][2];
            float d2 = dx*dx + dy*dy + dz*dz;
            if (d2 < bd){ bd = d2; best = t; }
        }
        sbest[tid] = best;
        sp3[tid][0] = px; sp3[tid][1] = py; sp3[tid][2] = pz;
    }
    __syncthreads();
    if (tid < 5){
        float sx = 0.f, sy = 0.f, sz = 0.f, cnt = 0.f;
        for (int c = 0; c < 62; ++c){
            if (sbest[c] == tid){
                sx += sp3[c][0]; sy += sp3[c][1]; sz += sp3[c][2]; cnt += 1.f;
            }
        }
        float* dst = pbuf + (size_t)b*20;
        dst[tid*3 + 0] = sx; dst[tid*3 + 1] = sy; dst[tid*3 + 2] = sz;
        dst[15 + tid]  = cnt;
    }
}

// ---------------------------------------------------------------------------
// Kernel C: reduce pbuf (b-ascending) -> pos FPS centers, center update,
// stable order + greedy assignment. 1 block x 64 threads.
// ---------------------------------------------------------------------------
__global__ __launch_bounds__(64) void finalize_kernel(
        const float* __restrict__ pos_emb, const float* __restrict__ pbuf,
        int* __restrict__ assign_out)
{
    __shared__ float P[62*3];
    __shared__ float Dp[62*62];
    __shared__ float rsv[62];
    __shared__ float mdv[62];
    __shared__ int   seli[5];
    __shared__ float cenS[5][3];
    __shared__ int   ordS[62][5];
    __shared__ float gs[15];
    __shared__ float gc[5];
    const int tid = threadIdx.x;

    if (tid < 20){
        float s = 0.f;
        for (int b = 0; b < 128; ++b) s += pbuf[(size_t)b*20 + tid];
        if (tid < 15) gs[tid] = s; else gc[tid-15] = s;
    }
    if (tid < 62){
        #pragma unroll
        for (int j = 0; j < 3; ++j) P[tid*3 + j] = pos_emb[(size_t)tid*3 + j];
    }
    __syncthreads();
    if (tid < 62){
        float xi = P[tid*3], yi = P[tid*3+1], zi = P[tid*3+2];
        float s = 0.f;
        for (int j = 0; j < 62; ++j){
            float dx = xi - P[j*3], dy = yi - P[j*3+1], dz = zi - P[j*3+2];
            float d = sqrtf(dx*dx + dy*dy + dz*dz);
            Dp[tid*62 + j] = d; s += d;
        }
        rsv[tid] = s;
    }
    __syncthreads();
    if (tid == 0){
        int bi = 0; float bv = rsv[0];
        for (int i = 1; i < 62; ++i) if (rsv[i] > bv){ bv = rsv[i]; bi = i; }
        seli[0] = bi;
        for (int i = 0; i < 62; ++i) mdv[i] = Dp[bi*62 + i];
        for (int it = 1; it < 5; ++it){
            int fi = 0; float fv = mdv[0];
            for (int i = 1; i < 62; ++i) if (mdv[i] > fv){ fv = mdv[i]; fi = i; }
            seli[it] = fi;
            for (int i = 0; i < 62; ++i) mdv[i] = fminf(mdv[i], Dp[fi*62 + i]);
        }
        float cen[5][3], avg[5][3];
        for (int t = 0; t < 5; ++t)
            for (int j = 0; j < 3; ++j) cen[t][j] = P[seli[t]*3 + j];
        for (int t = 0; t < 5; ++t){
            float c = gc[t];
            for (int j = 0; j < 3; ++j)
                avg[t][j] = (c > 0.f) ? gs[t*3 + j] / fmaxf(c, 1.f) : 0.f;
        }
        for (int i = 0; i < 5; ++i){
            int m = 0; float bv2 = 3.4e38f;
            for (int j = 0; j < 5; ++j){
                float dx = cen[i][0]-avg[j][0], dy = cen[i][1]-avg[j][1], dz = cen[i][2]-avg[j][2];
                float d2 = dx*dx + dy*dy + dz*dz;
                if (d2 < bv2){ bv2 = d2; m = j; }
            }
            for (int j = 0; j < 3; ++j) cenS[i][j] = 0.8f*cen[i][j] + 0.2f*avg[m][j];
        }
    }
    __syncthreads();
    if (tid < 62){
        float dd[5];
        #pragma unroll
        for (int t = 0; t < 5; ++t){
            float dx = P[tid*3]-cenS[t][0], dy = P[tid*3+1]-cenS[t][1], dz = P[tid*3+2]-cenS[t][2];
            dd[t] = sqrtf(dx*dx + dy*dy + dz*dz);
        }
        bool tk[5] = {false,false,false,false,false};
        #pragma unroll
        for (int s = 0; s < 5; ++s){
            int best = -1;
            #pragma unroll
            for (int t = 0; t < 5; ++t)
                if (!tk[t] && (best < 0 || dd[t] < dd[best])) best = t;
            tk[best] = true; ordS[tid][s] = best;
        }
    }
    __syncthreads();
    if (tid == 0){
        const int sizesA[5] = {13,13,12,12,12};
        int counts[5] = {0,0,0,0,0};
        for (int i = 0; i < 62; ++i){
            int cl = ordS[i][0];
            #pragma unroll
            for (int s = 0; s < 5; ++s){
                int t = ordS[i][s];
                if (counts[t] < sizesA[t]){ cl = t; break; }
            }
            counts[cl]++;
            assign_out[i] = cl;
        }
    }
}

// ---------------------------------------------------------------------------
// Kernel D: pf = relu(LN(feats @ W.T + b)). (R9 register-tiled version.)
// ---------------------------------------------------------------------------
__global__ __launch_bounds__(128) void proj_kernel(
        const float* __restrict__ feats, const float* __restrict__ proj_w,
        const float* __restrict__ proj_b, const float* __restrict__ lng,
        const float* __restrict__ lnb, float* __restrict__ pf)
{
    __shared__ float fs[8*FDIM];    // 16128 B; reused as pfs[8][128] after k-loop
    __shared__ float scr[4];
    const int tid = threadIdx.x;
    const int row0 = blockIdx.x * 8;

    for (int i = tid; i < 8*FDIM; i += 128)
        fs[i] = feats[(size_t)row0*FDIM + i];
    __syncthreads();

    const int dg = tid >> 2;        // 0..31 -> dims dg*4 .. dg*4+3
    const int rp = tid & 3;         // 0..3  -> rows rp*2, rp*2+1

    float acc[4][2];
    #pragma unroll
    for (int dd = 0; dd < 4; ++dd){
        float bb = proj_b[dg*4 + dd];
        acc[dd][0] = bb; acc[dd][1] = bb;
    }

    const float4* w0 = (const float4*)(proj_w + (size_t)(dg*4+0)*FDIM);
    const float4* w1 = (const float4*)(proj_w + (size_t)(dg*4+1)*FDIM);
    const float4* w2 = (const float4*)(proj_w + (size_t)(dg*4+2)*FDIM);
    const float4* w3 = (const float4*)(proj_w + (size_t)(dg*4+3)*FDIM);
    const float4* f0 = (const float4*)(fs + (rp*2+0)*FDIM);
    const float4* f1 = (const float4*)(fs + (rp*2+1)*FDIM);

    for (int kc = 0; kc < 63; ++kc){
        float4 p0 = f0[2*kc], q0 = f0[2*kc+1];
        float4 p1 = f1[2*kc], q1 = f1[2*kc+1];
        const float4* wd[4] = {w0, w1, w2, w3};
        #pragma unroll
        for (int dd = 0; dd < 4; ++dd){
            float4 wA = wd[dd][2*kc], wB = wd[dd][2*kc+1];
            float s = acc[dd][0];
            s = fmaf(p0.x,wA.x,s); s = fmaf(p0.y,wA.y,s); s = fmaf(p0.z,wA.z,s); s = fmaf(p0.w,wA.w,s);
            s = fmaf(q0.x,wB.x,s); s = fmaf(q0.y,wB.y,s); s = fmaf(q0.z,wB.z,s); s = fmaf(q0.w,wB.w,s);
            acc[dd][0] = s;
            s = acc[dd][1];
            s = fmaf(p1.x,wA.x,s); s = fmaf(p1.y,wA.y,s); s = fmaf(p1.z,wA.z,s); s = fmaf(p1.w,wA.w,s);
            s = fmaf(q1.x,wB.x,s); s = fmaf(q1.y,wB.y,s); s = fmaf(q1.z,wB.z,s); s = fmaf(q1.w,wB.w,s);
            acc[dd][1] = s;
        }
    }
    __syncthreads();    // all fs reads done before overwrite

    #pragma unroll
    for (int dd = 0; dd < 4; ++dd){
        fs[(rp*2+0)*128 + dg*4 + dd] = acc[dd][0];
        fs[(rp*2+1)*128 + dg*4 + dd] = acc[dd][1];
    }
    __syncthreads();

    const float gl = lng[tid], bl = lnb[tid];
    #pragma unroll
    for (int g = 0; g < 8; ++g){
        float v = fs[g*128 + tid];
        float s1 = v, s2 = v*v;
        bred2(s1, s2, scr, tid);
        float m = s1 * (1.f/128.f);
        float var = fmaxf(s2 * (1.f/128.f) - m*m, 0.f);
        float y = (v - m) / sqrtf(var + 1e-5f);
        y = y*gl + bl;
        pf[(size_t)(row0 + g)*DM + tid] = fmaxf(y, 0.f);
    }
}

// ---------------------------------------------------------------------------
// Kernel F: token pooling + 3-layer transformer. 128 blocks x 512 threads.
// (R12 k-split x4 version.)
// ---------------------------------------------------------------------------
__global__ __launch_bounds__(512) void former_kernel(
        const float* __restrict__ pf, const int* __restrict__ assign,
        const float* __restrict__ pos_enc,
        const float* __restrict__ Wqkv, const float* __restrict__ bqkv,
        const float* __restrict__ Wo,   const float* __restrict__ bo,
        const float* __restrict__ W1,   const float* __restrict__ b1,
        const float* __restrict__ W2,   const float* __restrict__ b2,
        const float* __restrict__ ln1g, const float* __restrict__ ln1b,
        const float* __restrict__ ln2g, const float* __restrict__ ln2b,
        float* __restrict__ out)
{
    __shared__ float h[5*128];
    __shared__ float qkvL[5*384];
    __shared__ float attL[100];
    __shared__ float oL[5*128];
    __shared__ float hidL[5*256];
    __shared__ float part[3*1920];    // partial-sum buffer for kq=1..3
    __shared__ int   asg[62];
    __shared__ float scr[4];

    const int b   = blockIdx.x;
    const int tid = threadIdx.x;
    const int d   = tid & 127;
    const int kq  = tid >> 7;         // 0..3

    if (tid < 62) asg[tid] = assign[tid];
    __syncthreads();

    // token pooling (kq==0 threads only; same order as before)
    if (kq == 0){
        float a0=0,a1=0,a2=0,a3=0,a4=0;
        const float* pfb = pf + (size_t)b*62*DM + d;
        for (int c = 0; c < 62; ++c){
            float v = pfb[(size_t)c*DM];
            int a = asg[c];
            a0 += (a==0)?v:0.f; a1 += (a==1)?v:0.f; a2 += (a==2)?v:0.f;
            a3 += (a==3)?v:0.f; a4 += (a==4)?v:0.f;
        }
        h[0*128+d] = a0/13.f + pos_enc[0*128+d];
        h[1*128+d] = a1/13.f + pos_enc[1*128+d];
        h[2*128+d] = a2/12.f + pos_enc[2*128+d];
        h[3*128+d] = a3/12.f + pos_enc[3*128+d];
        h[4*128+d] = a4/12.f + pos_enc[4*128+d];
    }
    __syncthreads();

    for (int L = 0; L < 3; ++L){
        // ---- qkv: each kq computes a quarter of the k-range ----
        const float* Wq = Wqkv + (size_t)L*384*128;
        {
            float acc[3][5];
            #pragma unroll
            for (int rr = 0; rr < 3; ++rr){
                float bb = (kq == 0) ? bqkv[L*384 + rr*128 + d] : 0.f;
                #pragma unroll
                for (int t = 0; t < 5; ++t) acc[rr][t] = bb;
            }
            for (int kc = kq*4; kc < kq*4 + 4; ++kc){
                float hr[5][8];
                #pragma unroll
                for (int t = 0; t < 5; ++t){
                    float4 p = *(const float4*)&h[t*128 + kc*8];
                    float4 q = *(const float4*)&h[t*128 + kc*8 + 4];
                    hr[t][0]=p.x; hr[t][1]=p.y; hr[t][2]=p.z; hr[t][3]=p.w;
                    hr[t][4]=q.x; hr[t][5]=q.y; hr[t][6]=q.z; hr[t][7]=q.w;
                }
                #pragma unroll
                for (int rr = 0; rr < 3; ++rr){
                    float4 wA = *(const float4*)(Wq + ((size_t)(rr*128 + d))*128 + kc*8);
                    float4 wB = *(const float4*)(Wq + ((size_t)(rr*128 + d))*128 + kc*8 + 4);
                    #pragma unroll
                    for (int t = 0; t < 5; ++t){
                        float s = acc[rr][t];
                        s=fmaf(hr[t][0],wA.x,s); s=fmaf(hr[t][1],wA.y,s);
                        s=fmaf(hr[t][2],wA.z,s); s=fmaf(hr[t][3],wA.w,s);
                        s=fmaf(hr[t][4],wB.x,s); s=fmaf(hr[t][5],wB.y,s);
                        s=fmaf(hr[t][6],wB.z,s); s=fmaf(hr[t][7],wB.w,s);
                        acc[rr][t] = s;
                    }
                }
            }
            if (kq > 0){
                #pragma unroll
                for (int rr = 0; rr < 3; ++rr)
                    #pragma unroll
                    for (int t = 0; t < 5; ++t)
                        part[(kq-1)*1920 + t*384 + rr*128 + d] = acc[rr][t];
            }
            __syncthreads();
            if (kq == 0){
                #pragma unroll
                for (int rr = 0; rr < 3; ++rr)
                    #pragma unroll
                    for (int t = 0; t < 5; ++t){
                        int o = t*384 + rr*128 + d;
                        qkvL[o] = ((acc[rr][t] + part[o]) + part[1920 + o]) + part[3840 + o];
                    }
            }
            __syncthreads();
        }

        // ---- scores (tid<100 => kq==0) ----
        if (tid < 100){
            int hh = tid/25, rem = tid - hh*25, tq = rem/5, tk = rem - (rem/5)*5;
            const float* qq = &qkvL[tq*384 + hh*32];
            const float* kk = &qkvL[tk*384 + 128 + hh*32];
            float s = 0.f;
            #pragma unroll
            for (int j = 0; j < 32; ++j) s = fmaf(qq[j], kk[j], s);
            attL[tid] = s * 0.17677669529663687f;   // 1/sqrt(32)
        }
        __syncthreads();
        if (tid < 20){
            int hh = tid/5, tq = tid - hh*5;
            float* row = &attL[hh*25 + tq*5];
            float mx = row[0];
            #pragma unroll
            for (int j = 1; j < 5; ++j) mx = fmaxf(mx, row[j]);
            float sm = 0.f;
            #pragma unroll
            for (int j = 0; j < 5; ++j){ float e = expf(row[j]-mx); row[j] = e; sm += e; }
            float inv = 1.f/sm;
            #pragma unroll
            for (int j = 0; j < 5; ++j) row[j] *= inv;
        }
        __syncthreads();

        // ---- attention output: kq0 -> tokens {0,4}; kq1..3 -> {1,2,3} ----
        {
            int hh = d >> 5;
            int tA = kq;               // 0..3
            {
                float s = 0.f;
                #pragma unroll
                for (int tk = 0; tk < 5; ++tk)
                    s = fmaf(attL[hh*25 + tA*5 + tk], qkvL[tk*384 + 256 + d], s);
                oL[tA*128 + d] = s;
            }
            if (kq == 0){
                float s = 0.f;
                #pragma unroll
                for (int tk = 0; tk < 5; ++tk)
                    s = fmaf(attL[hh*25 + 4*5 + tk], qkvL[tk*384 + 256 + d], s);
                oL[4*128 + d] = s;
            }
        }
        __syncthreads();

        // ---- out proj (k-quarter) + residual + LN1 ----
        float val[5];
        {
            float bv = (kq == 0) ? bo[L*128 + d] : 0.f;
            #pragma unroll
            for (int t = 0; t < 5; ++t) val[t] = bv;
            const float* WoR = Wo + ((size_t)L*128 + d)*128;
            for (int kc = kq*4; kc < kq*4 + 4; ++kc){
                float orr[5][8];
                #pragma unroll
                for (int t = 0; t < 5; ++t){
                    float4 p = *(const float4*)&oL[t*128 + kc*8];
                    float4 q = *(const float4*)&oL[t*128 + kc*8 + 4];
                    orr[t][0]=p.x; orr[t][1]=p.y; orr[t][2]=p.z; orr[t][3]=p.w;
                    orr[t][4]=q.x; orr[t][5]=q.y; orr[t][6]=q.z; orr[t][7]=q.w;
                }
                float4 wA = *(const float4*)(WoR + kc*8);
                float4 wB = *(const float4*)(WoR + kc*8 + 4);
                #pragma unroll
                for (int t = 0; t < 5; ++t){
                    float s = val[t];
                    s=fmaf(orr[t][0],wA.x,s); s=fmaf(orr[t][1],wA.y,s);
                    s=fmaf(orr[t][2],wA.z,s); s=fmaf(orr[t][3],wA.w,s);
                    s=fmaf(orr[t][4],wB.x,s); s=fmaf(orr[t][5],wB.y,s);
                    s=fmaf(orr[t][6],wB.z,s); s=fmaf(orr[t][7],wB.w,s);
                    val[t] = s;
                }
            }
            if (kq > 0){
                #pragma unroll
                for (int t = 0; t < 5; ++t)
                    part[(kq-1)*1920 + t*128 + d] = val[t];
            }
            __syncthreads();
            if (kq == 0){
                #pragma unroll
                for (int t = 0; t < 5; ++t){
                    int o = t*128 + d;
                    val[t] = (((val[t] + part[o]) + part[1920 + o]) + part[3840 + o])
                             + h[t*128 + d];
                }
            }
            __syncthreads();
        }
        {
            float ng = ln1g[L*128 + d], nb = ln1b[L*128 + d];
            #pragma unroll
            for (int t = 0; t < 5; ++t){
                float s1 = val[t], s2 = val[t]*val[t];
                bred2h(s1, s2, scr, tid);
                float m = s1*(1.f/128.f);
                float var = fmaxf(s2*(1.f/128.f) - m*m, 0.f);
                float y = (val[t] - m) / sqrtf(var + 1e-5f);
                if (kq == 0) h[t*128 + d] = y*ng + nb;
            }
        }
        __syncthreads();

        // ---- FF1 (k-quarter) ----
        {
            float f1[2][5];
            #pragma unroll
            for (int rr = 0; rr < 2; ++rr){
                float bb = (kq == 0) ? b1[L*256 + rr*128 + d] : 0.f;
                #pragma unroll
                for (int t = 0; t < 5; ++t) f1[rr][t] = bb;
            }
            const float* W1b = W1 + (size_t)L*256*128;
            for (int kc = kq*4; kc < kq*4 + 4; ++kc){
                float hr[5][8];
                #pragma unroll
                for (int t = 0; t < 5; ++t){
                    float4 p = *(const float4*)&h[t*128 + kc*8];
                    float4 q = *(const float4*)&h[t*128 + kc*8 + 4];
                    hr[t][0]=p.x; hr[t][1]=p.y; hr[t][2]=p.z; hr[t][3]=p.w;
                    hr[t][4]=q.x; hr[t][5]=q.y; hr[t][6]=q.z; hr[t][7]=q.w;
                }
                #pragma unroll
                for (int rr = 0; rr < 2; ++rr){
                    float4 wA = *(const float4*)(W1b + ((size_t)(rr*128 + d))*128 + kc*8);
                    float4 wB = *(const float4*)(W1b + ((size_t)(rr*128 + d))*128 + kc*8 + 4);
                    #pragma unroll
                    for (int t = 0; t < 5; ++t){
                        float s = f1[rr][t];
                        s=fmaf(hr[t][0],wA.x,s); s=fmaf(hr[t][1],wA.y,s);
                        s=fmaf(hr[t][2],wA.z,s); s=fmaf(hr[t][3],wA.w,s);
                        s=fmaf(hr[t][4],wB.x,s); s=fmaf(hr[t][5],wB.y,s);
                        s=fmaf(hr[t][6],wB.z,s); s=fmaf(hr[t][7],wB.w,s);
                        f1[rr][t] = s;
                    }
                }
            }
            if (kq > 0){
                #pragma unroll
                for (int rr = 0; rr < 2; ++rr)
                    #pragma unroll
                    for (int t = 0; t < 5; ++t)
                        part[(kq-1)*1920 + rr*640 + t*128 + d] = f1[rr][t];
            }
            __syncthreads();
            if (kq == 0){
                #pragma unroll
                for (int rr = 0; rr < 2; ++rr)
                    #pragma unroll
                    for (int t = 0; t < 5; ++t){
                        int o = rr*640 + t*128 + d;
                        float v = ((f1[rr][t] + part[o]) + part[1920 + o]) + part[3840 + o];
                        hidL[t*256 + rr*128 + d] = fmaxf(v, 0.f);
                    }
            }
            __syncthreads();
        }

        // ---- FF2 (k-quarter) + residual + LN2 ----
        {
            float v2[5];
            float bv = (kq == 0) ? b2[L*128 + d] : 0.f;
            #pragma unroll
            for (int t = 0; t < 5; ++t) v2[t] = bv;
            const float* W2R = W2 + ((size_t)L*128 + d)*256;
            for (int kc = kq*8; kc < kq*8 + 8; ++kc){
                float hr[5][8];
                #pragma unroll
                for (int t = 0; t < 5; ++t){
                    float4 p = *(const float4*)&hidL[t*256 + kc*8];
                    float4 q = *(const float4*)&hidL[t*256 + kc*8 + 4];
                    hr[t][0]=p.x; hr[t][1]=p.y; hr[t][2]=p.z; hr[t][3]=p.w;
                    hr[t][4]=q.x; hr[t][5]=q.y; hr[t][6]=q.z; hr[t][7]=q.w;
                }
                float4 wA = *(const float4*)(W2R + kc*8);
                float4 wB = *(const float4*)(W2R + kc*8 + 4);
                #pragma unroll
                for (int t = 0; t < 5; ++t){
                    float s = v2[t];
                    s=fmaf(hr[t][0],wA.x,s); s=fmaf(hr[t][1],wA.y,s);
                    s=fmaf(hr[t][2],wA.z,s); s=fmaf(hr[t][3],wA.w,s);
                    s=fmaf(hr[t][4],wB.x,s); s=fmaf(hr[t][5],wB.y,s);
                    s=fmaf(hr[t][6],wB.z,s); s=fmaf(hr[t][7],wB.w,s);
                    v2[t] = s;
                }
            }
            if (kq > 0){
                #pragma unroll
                for (int t = 0; t < 5; ++t) part[(kq-1)*1920 + t*128 + d] = v2[t];
            }
            __syncthreads();
            if (kq == 0){
                #pragma unroll
                for (int t = 0; t < 5; ++t){
                    int o = t*128 + d;
                    v2[t] = (((v2[t] + part[o]) + part[1920 + o]) + part[3840 + o])
                            + h[t*128 + d];
                }
            }
            __syncthreads();
            float ng = ln2g[L*128 + d], nb = ln2b[L*128 + d];
            #pragma unroll
            for (int t = 0; t < 5; ++t){
                float s1 = v2[t], s2 = v2[t]*v2[t];
                bred2h(s1, s2, scr, tid);
                float m = s1*(1.f/128.f);
                float var = fmaxf(s2*(1.f/128.f) - m*m, 0.f);
                float y = (v2[t] - m) / sqrtf(var + 1e-5f);
                if (kq == 0) h[t*128 + d] = y*ng + nb;
            }
        }
        __syncthreads();
    }

    if (kq == 0){
        #pragma unroll
        for (int t = 0; t < 5; ++t)
            out[((size_t)b*5 + t)*128 + d] = h[t*128 + d];
    }
}

// ---------------------------------------------------------------------------
extern "C" void kernel_launch(void* const* d_in, const int* in_sizes, int n_in,
                              void* d_out, int out_size, void* d_ws, size_t ws_size,
                              hipStream_t stream)
{
    const float* x        = (const float*)d_in[0];
    const float* pos_emb  = (const float*)d_in[1];
    const float* proj_w   = (const float*)d_in[2];
    const float* proj_b   = (const float*)d_in[3];
    const float* proj_lng = (const float*)d_in[4];
    const float* proj_lnb = (const float*)d_in[5];
    const float* pos_enc  = (const float*)d_in[6];
    const float* Wqkv     = (const float*)d_in[7];
    const float* bqkv     = (const float*)d_in[8];
    const float* Wo       = (const float*)d_in[9];
    const float* bo       = (const float*)d_in[10];
    const float* W1       = (const float*)d_in[11];
    const float* b1       = (const float*)d_in[12];
    const float* W2       = (const float*)d_in[13];
    const float* b2       = (const float*)d_in[14];
    const float* ln1g     = (const float*)d_in[15];
    const float* ln1b     = (const float*)d_in[16];
    const float* ln2g     = (const float*)d_in[17];
    const float* ln2b     = (const float*)d_in[18];

    float* ws    = (float*)d_ws;
    float* feats = ws;                              // 128*62*504
    float* pf    = feats + (size_t)N_SIG*FDIM;      // 128*62*128
    float* gsums = pf + (size_t)N_SIG*DM;           // 15 (unused, kept for layout)
    float* gcnt  = gsums + 15;                      // 5  (unused)
    int*   assign = (int*)(gcnt + 5);               // 62
    float* basis = (float*)(assign + 64);           // 23*50*4 = 4600
    float* pbuf  = basis + 4600;                    // 128*20 = 2560
    float* dmg   = pf;   // 128*3844 floats, aliases pf (pf written later by proj)

    float* out = (float*)d_out;

    basis_kernel<<<5, 256, 0, stream>>>(basis);
    feat_kernel<<<N_SIG, 256, 0, stream>>>(x, basis, feats);
    dist_kernel<<<256, 512, 0, stream>>>(feats, dmg);
    fps_kernel<<<128, 64, 0, stream>>>(dmg, pos_emb, pbuf);
    finalize_kernel<<<1, 64, 0, stream>>>(pos_emb, pbuf, assign);
    proj_kernel<<<992, 128, 0, stream>>>(feats, proj_w, proj_b, proj_lng, proj_lnb, pf);
    former_kernel<<<128, 512, 0, stream>>>(pf, assign, pos_enc,
        Wqkv, bqkv, Wo, bo, W1, b1, W2, b2, ln1g, ln1b, ln2g, ln2b, out);
}

// Round 12
// 514.034 us; speedup vs baseline: 1.0353x; 1.0353x over previous
//
#include <hip/hip_runtime.h>
#include <hip/hip_bf16.h>

// ===========================================================================
// EEGRCformer forward on MI355X. ALL tensors float32.
// R14: (1) feat stage B reverted to R12 item-major (R13's j-major cost VGPR
// 56->68, occ 44->33%, +14us — third confirmation that feat stage B is
// occupancy-pinned at 56 VGPRs). (2) finalize_kernel folded into former:
// each former block redundantly computes assign from pbuf+pos_emb (same
// arithmetic order -> identical result); finalize scratch aliased into the
// dead part[] buffer. One fewer launch + serial kernel.
// Rest = R12 (former k-split x4, dist/fps/proj, no contended atomics).
// ws layout (floats): feats[128*62*504] | pf[128*62*128] (aliased as dmg
// before proj) | gsums[15] | gcnt[5] | assign[62 ints, unused] |
// basis[23*50*4] | pbuf[128*20]
// ===========================================================================

typedef unsigned int u32;

#define N_SIG   7936          // 128*62
#define FDIM    504           // 36*14
#define DM      128

__device__ __constant__ int   bstart_c[7] = {1,4,8,12,16,20,30};
__device__ __constant__ int   bcnt_c[7]   = {3,4,4,4,4,10,15};
__device__ __constant__ float bandcnt_c[7] = {3.f,4.f,4.f,4.f,4.f,10.f,15.f};

// twiddles T[m] = e^{-i 2 pi m / 5} = (cos, -sin)
__device__ __constant__ float twr_c[5] = {
    1.0f, 0.30901699437494745f, -0.8090169943749475f,
    -0.8090169943749475f, 0.30901699437494745f};
__device__ __constant__ float twi_c[5] = {
    0.0f, -0.9510565162951535f, -0.5877852522924731f,
    0.5877852522924731f, 0.9510565162951535f};

// block reduce of (a,b) over 128 threads (2 waves); scr must be >=4 floats
static __device__ __forceinline__ void bred2(float& a, float& b, volatile float* scr, int tid){
    #pragma unroll
    for (int off = 32; off > 0; off >>= 1){
        a += __shfl_down(a, off, 64);
        b += __shfl_down(b, off, 64);
    }
    if ((tid & 63) == 0){ scr[tid>>6] = a; scr[2 + (tid>>6)] = b; }
    __syncthreads();
    a = scr[0] + scr[1];
    b = scr[2] + scr[3];
    __syncthreads();
}

// wide-block variant: only tid<128 contribute (identical tree to bred2);
// ALL threads must call it (contains barriers); result broadcast to all.
static __device__ __forceinline__ void bred2h(float& a, float& b, volatile float* scr, int tid){
    #pragma unroll
    for (int off = 32; off > 0; off >>= 1){
        a += __shfl_down(a, off, 64);
        b += __shfl_down(b, off, 64);
    }
    if (tid < 128 && (tid & 63) == 0){ scr[tid>>6] = a; scr[2 + (tid>>6)] = b; }
    __syncthreads();
    a = scr[0] + scr[1];
    b = scr[2] + scr[3];
    __syncthreads();
}

// 5-chunk combine of rect-DFT bin kk for window w (reads chunk DFTs in Cb).
static __device__ __forceinline__ float2 combine5(const float* __restrict__ Cb,
                                                  int w, int kk){
    const int k5 = kk % 5;
    const float* cb = Cb + ((size_t)(w*46 + kk))*2;
    float2 cv[5];
    #pragma unroll
    for (int c = 0; c < 5; ++c) cv[c] = *(const float2*)(cb + c*92);
    float ar = 0.f, ai = 0.f;
    int m = 0;
    #pragma unroll
    for (int c = 0; c < 5; ++c){
        float tr = twr_c[m], ti = twi_c[m];
        ar = fmaf(tr, cv[c].x, ar); ar = fmaf(-ti, cv[c].y, ar);
        ai = fmaf(tr, cv[c].y, ai); ai = fmaf(ti, cv[c].x, ai);
        m += k5; if (m >= 5) m -= 5;
    }
    float2 o; o.x = ar; o.y = ai;
    return o;
}

// ---------------------------------------------------------------------------
// Kernel 0: precompute chunk-DFT basis -> global.
// ---------------------------------------------------------------------------
__global__ __launch_bounds__(256) void basis_kernel(float* __restrict__ basis)
{
    int idx = blockIdx.x*256 + threadIdx.x;      // over 23*50 = 1150
    if (idx >= 1150) return;
    int kp = idx / 50;
    int n  = idx - kp*50;
    const float TPO = 0.025132741228718345f;     // 2*pi/250
    int k0 = 2*kp, k1 = 2*kp + 1;
    float s0, c0, s1, c1;
    sincosf((float)((k0*n) % 250) * TPO, &s0, &c0);
    sincosf((float)((k1*n) % 250) * TPO, &s1, &c1);
    float4 v; v.x = c0; v.y = -s0; v.z = c1; v.w = -s1;
    ((float4*)basis)[idx] = v;
}

// ---------------------------------------------------------------------------
// Kernel A: chunk DFTs -> window combine (Xw packed into Cb) -> Hann+PSD+DE
// -> z-norm -> feats. N_SIG blocks x 256 threads, 1 signal/block.
// LDS = 22.8 KB -> 7 blocks/CU. (R12 form: item-major stage B, VGPR 56.)
// ---------------------------------------------------------------------------
__global__ __launch_bounds__(256) void feat_kernel(
        const float* __restrict__ x, const float* __restrict__ basis,
        float* __restrict__ feats)
{
    __shared__ __align__(16) float xs[2000];        //  8000 B
    __shared__ __align__(16) float Cb[3680];        // 14720 B chunk DFTs / Xw
    __shared__ float scr[16];

    const int tid = threadIdx.x;
    const int sig = blockIdx.x;

    // ---- stage A: stage x (coalesced float4) ----
    {
        const float4* xg = (const float4*)(x + (size_t)sig*2000);
        for (int i = tid; i < 500; i += 256) ((float4*)xs)[i] = xg[i];
    }
    __syncthreads();

    // ---- stage B: chunk DFTs. item = kp*40 + j ----
    for (int item = tid; item < 920; item += 256){
        const int kp = item / 40;            // 0..22  -> bins 2kp, 2kp+1
        const int j  = item - kp*40;         // 0..39  chunk
        const float2* xp = (const float2*)(xs + 50*j);     // 50j even -> aligned
        const float4* bp = ((const float4*)basis) + kp*50;
        float cr0=0.f, ci0=0.f, cr1=0.f, ci1=0.f;
        #pragma unroll 5
        for (int t = 0; t < 25; ++t){
            float2 xv = xp[t];
            float4 b0 = bp[2*t], b1 = bp[2*t+1];
            cr0 = fmaf(xv.x, b0.x, cr0); ci0 = fmaf(xv.x, b0.y, ci0);
            cr1 = fmaf(xv.x, b0.z, cr1); ci1 = fmaf(xv.x, b0.w, ci1);
            cr0 = fmaf(xv.y, b1.x, cr0); ci0 = fmaf(xv.y, b1.y, ci0);
            cr1 = fmaf(xv.y, b1.z, cr1); ci1 = fmaf(xv.y, b1.w, ci1);
        }
        float4 o; o.x = cr0; o.y = ci0; o.z = cr1; o.w = ci1;
        *(float4*)(Cb + ((size_t)(j*46 + 2*kp))*2) = o;
    }
    __syncthreads();   // Cb ready

    // ---- stage C1: windows 18..35 computed; write into slots 22..39 merged
    //      with compute of windows 0..17 (disjoint chunk reads); write 0..17.
    {
        const int i0 = tid, i1 = tid + 256, i2 = tid + 512, i3 = tid + 768;
        float2 r0, r1, r2, r3;
        { int w = 18 + i0/46, k = i0 - (i0/46)*46; r0 = combine5(Cb, w, k); }
        { int w = 18 + i1/46, k = i1 - (i1/46)*46; r1 = combine5(Cb, w, k); }
        { int w = 18 + i2/46, k = i2 - (i2/46)*46; r2 = combine5(Cb, w, k); }
        if (i3 < 828){ int w = 18 + i3/46, k = i3 - (i3/46)*46; r3 = combine5(Cb, w, k); }
        __syncthreads();   // all reads of chunks 22..39 complete
        { int w = 18 + i0/46, k = i0 - (i0/46)*46; *(float2*)(Cb + (w+4)*92 + 2*k) = r0; }
        { int w = 18 + i1/46, k = i1 - (i1/46)*46; *(float2*)(Cb + (w+4)*92 + 2*k) = r1; }
        { int w = 18 + i2/46, k = i2 - (i2/46)*46; *(float2*)(Cb + (w+4)*92 + 2*k) = r2; }
        if (i3 < 828){ int w = 18 + i3/46, k = i3 - (i3/46)*46; *(float2*)(Cb + (w+4)*92 + 2*k) = r3; }
        float2 s0, s1, s2, s3;
        { int w = i0/46, k = i0 - (i0/46)*46; s0 = combine5(Cb, w, k); }
        { int w = i1/46, k = i1 - (i1/46)*46; s1 = combine5(Cb, w, k); }
        { int w = i2/46, k = i2 - (i2/46)*46; s2 = combine5(Cb, w, k); }
        if (i3 < 828){ int w = i3/46, k = i3 - (i3/46)*46; s3 = combine5(Cb, w, k); }
        __syncthreads();   // low-window reads done
        { int w = i0/46, k = i0 - (i0/46)*46; *(float2*)(Cb + w*92 + 2*k) = s0; }
        { int w = i1/46, k = i1 - (i1/46)*46; *(float2*)(Cb + w*92 + 2*k) = s1; }
        { int w = i2/46, k = i2 - (i2/46)*46; *(float2*)(Cb + w*92 + 2*k) = s2; }
        if (i3 < 828){ int w = i3/46, k = i3 - (i3/46)*46; *(float2*)(Cb + w*92 + 2*k) = s3; }
    }
    __syncthreads();   // Xw fully materialized inside Cb

    // ---- stage C2+D: per-(window,band) Hann+PSD+DE, then block z-norm ----
    float psd = 0.f, de = 0.f;
    float s1p = 0.f, s2p = 0.f, s1d = 0.f, s2d = 0.f;
    int w = 0, bi = 0;
    if (tid < 252){
        w  = tid / 7;
        bi = tid - w*7;
        const int st = bstart_c[bi], cn = bcnt_c[bi];
        const float2* Xrow = (const float2*)(Cb + ((w < 18) ? w*92 : (w+4)*92));
        float2 xm = Xrow[st-1], xc = Xrow[st];
        float p = 0.f;
        for (int q = 0; q < cn; ++q){
            float2 xp = Xrow[st+q+1];
            float Hr = 0.5f*xc.x - 0.25f*(xm.x + xp.x);
            float Hi = 0.5f*xc.y - 0.25f*(xm.y + xp.y);
            p = fmaf(Hr, Hr, p); p = fmaf(Hi, Hi, p);
            xm = xc; xc = xp;
        }
        psd = p * (1.0f/250.0f) / bandcnt_c[bi];
        de  = 0.5f * logf(17.079468445347134f*psd + 1e-9f);
        s1p = psd; s2p = psd*psd; s1d = de; s2d = de*de;
    }
    // block reduce 4 sums over 256 threads (4 waves)
    #pragma unroll
    for (int off = 32; off > 0; off >>= 1){
        s1p += __shfl_down(s1p, off, 64); s2p += __shfl_down(s2p, off, 64);
        s1d += __shfl_down(s1d, off, 64); s2d += __shfl_down(s2d, off, 64);
    }
    {
        const int wid = tid >> 6;
        if ((tid & 63) == 0){
            scr[0*4 + wid] = s1p; scr[1*4 + wid] = s2p;
            scr[2*4 + wid] = s1d; scr[3*4 + wid] = s2d;
        }
    }
    __syncthreads();
    s1p = scr[0] + scr[1] + scr[2]  + scr[3];
    s2p = scr[4] + scr[5] + scr[6]  + scr[7];
    s1d = scr[8] + scr[9] + scr[10] + scr[11];
    s2d = scr[12] + scr[13] + scr[14] + scr[15];

    if (tid < 252){
        float mp = s1p / 252.f;
        float vp = fmaxf((s2p - 252.f*mp*mp) / 251.f, 0.f);
        float sp = sqrtf(vp) + 1e-9f;
        float md = s1d / 252.f;
        float vd = fmaxf((s2d - 252.f*md*md) / 251.f, 0.f);
        float sd = sqrtf(vd) + 1e-9f;
        float* ob = feats + (size_t)sig * FDIM;
        ob[w*14 + bi]     = (psd - mp) / sp;
        ob[w*14 + 7 + bi] = (de  - md) / sd;
    }
}

// ---------------------------------------------------------------------------
// Kernel B1: 62x62 feature distance matrix -> global dmg. (R9 version.)
// ---------------------------------------------------------------------------
__global__ __launch_bounds__(512) void dist_kernel(
        const float* __restrict__ feats, float* __restrict__ dmg)
{
    __shared__ float Fc[62*130];     // 32.2 KB

    const int tid = threadIdx.x;
    const int b   = blockIdx.x >> 1;
    const int h   = blockIdx.x & 1;
    const int nt  = h ? 465 : 496;

    int ti = 0, tj = 0;
    const bool act = tid < nt;
    if (act){ ti = (h ? 16 : 0) + tid/31; tj = tid - (tid/31)*31; }

    float a00 = 0.f, a01 = 0.f, a10 = 0.f, a11 = 0.f;

    for (int ch = 0; ch < 4; ++ch){
        if (ch) __syncthreads();
        for (int i = tid; i < 62*63; i += 512){
            int r = i / 63, dc2 = i - r*63;
            *(float2*)(Fc + r*130 + 2*dc2) =
                *(const float2*)(feats + ((size_t)b*62 + r)*FDIM + ch*126 + 2*dc2);
        }
        __syncthreads();
        if (act){
            const float2* ri0 = (const float2*)(Fc + (2*ti)*130);
            const float2* ri1 = (const float2*)(Fc + (2*ti+1)*130);
            const float2* rj0 = (const float2*)(Fc + (2*tj)*130);
            const float2* rj1 = (const float2*)(Fc + (2*tj+1)*130);
            for (int g = 0; g < 9; ++g){      // 9 x 7 = 63
                const int q0 = g*7;
                float2 A0[7], A1[7], C0[7], C1[7];
                #pragma unroll
                for (int u = 0; u < 7; ++u){
                    A0[u] = ri0[q0+u]; A1[u] = ri1[q0+u];
                    C0[u] = rj0[q0+u]; C1[u] = rj1[q0+u];
                }
                #pragma unroll
                for (int u = 0; u < 7; ++u){
                    float d;
                    d = A0[u].x-C0[u].x; a00 = fmaf(d,d,a00); d = A0[u].y-C0[u].y; a00 = fmaf(d,d,a00);
                    d = A0[u].x-C1[u].x; a01 = fmaf(d,d,a01); d = A0[u].y-C1[u].y; a01 = fmaf(d,d,a01);
                    d = A1[u].x-C0[u].x; a10 = fmaf(d,d,a10); d = A1[u].y-C0[u].y; a10 = fmaf(d,d,a10);
                    d = A1[u].x-C1[u].x; a11 = fmaf(d,d,a11); d = A1[u].y-C1[u].y; a11 = fmaf(d,d,a11);
                }
            }
        }
    }
    if (act){
        float* dst = dmg + (size_t)b*3844;
        dst[(2*ti)*62   + 2*tj]   = sqrtf(a00);
        dst[(2*ti)*62   + 2*tj+1] = sqrtf(a01);
        dst[(2*ti+1)*62 + 2*tj]   = sqrtf(a10);
        dst[(2*ti+1)*62 + 2*tj+1] = sqrtf(a11);
    }
}

// ---------------------------------------------------------------------------
// Kernel B2: per-batch FPS(5) -> temp assign -> per-block reduction -> pbuf.
// 128 blocks x 64 threads. No contended atomics.
// ---------------------------------------------------------------------------
__global__ __launch_bounds__(64) void fps_kernel(
        const float* __restrict__ dmg, const float* __restrict__ pos_emb,
        float* __restrict__ pbuf)
{
    __shared__ float Dm[3844];
    __shared__ float mdv[62];
    __shared__ float rsv[62];
    __shared__ int   seli[5];
    __shared__ float ccen[5][3];
    __shared__ int   sbest[62];
    __shared__ float sp3[62][3];

    const int tid = threadIdx.x;
    const int b   = blockIdx.x;

    {
        const float4* src = (const float4*)(dmg + (size_t)b*3844);
        for (int i = tid; i < 961; i += 64) ((float4*)Dm)[i] = src[i];
    }
    __syncthreads();

    if (tid < 62){ float s = 0.f; for (int j = 0; j < 62; ++j) s += Dm[tid*62 + j]; rsv[tid] = s; }
    __syncthreads();
    if (tid == 0){
        int bi = 0; float bv = rsv[0];
        for (int i = 1; i < 62; ++i) if (rsv[i] > bv){ bv = rsv[i]; bi = i; }
        seli[0] = bi;
    }
    __syncthreads();
    if (tid < 62) mdv[tid] = Dm[seli[0]*62 + tid];
    __syncthreads();
    for (int it = 1; it < 5; ++it){
        if (tid == 0){
            int bi = 0; float bv = mdv[0];
            for (int i = 1; i < 62; ++i) if (mdv[i] > bv){ bv = mdv[i]; bi = i; }
            seli[it] = bi;
        }
        __syncthreads();
        if (tid < 62) mdv[tid] = fminf(mdv[tid], Dm[seli[it]*62 + tid]);
        __syncthreads();
    }
    if (tid < 5){
        int c0 = seli[tid];
        #pragma unroll
        for (int j = 0; j < 3; ++j) ccen[tid][j] = pos_emb[((size_t)b*62 + c0)*3 + j];
    }
    __syncthreads();
    if (tid < 62){
        float px = pos_emb[((size_t)b*62 + tid)*3 + 0];
        float py = pos_emb[((size_t)b*62 + tid)*3 + 1];
        float pz = pos_emb[((size_t)b*62 + tid)*3 + 2];
        int best = 0; float bd = 3.4e38f;
        #pragma unroll
        for (int t = 0; t < 5; ++t){
            float dx = px - ccen[t][0], dy = py - ccen[t][1], dz = pz - ccen[t][2];
            float d2 = dx*dx + dy*dy + dz*dz;
            if (d2 < bd){ bd = d2; best = t; }
        }
        sbest[tid] = best;
        sp3[tid][0] = px; sp3[tid][1] = py; sp3[tid][2] = pz;
    }
    __syncthreads();
    if (tid < 5){
        float sx = 0.f, sy = 0.f, sz = 0.f, cnt = 0.f;
        for (int c = 0; c < 62; ++c){
            if (sbest[c] == tid){
                sx += sp3[c][0]; sy += sp3[c][1]; sz += sp3[c][2]; cnt += 1.f;
            }
        }
        float* dst = pbuf + (size_t)b*20;
        dst[tid*3 + 0] = sx; dst[tid*3 + 1] = sy; dst[tid*3 + 2] = sz;
        dst[15 + tid]  = cnt;
    }
}

// ---------------------------------------------------------------------------
// Kernel D: pf = relu(LN(feats @ W.T + b)). (R9 register-tiled version.)
// ---------------------------------------------------------------------------
__global__ __launch_bounds__(128) void proj_kernel(
        const float* __restrict__ feats, const float* __restrict__ proj_w,
        const float* __restrict__ proj_b, const float* __restrict__ lng,
        const float* __restrict__ lnb, float* __restrict__ pf)
{
    __shared__ float fs[8*FDIM];    // 16128 B; reused as pfs[8][128] after k-loop
    __shared__ float scr[4];
    const int tid = threadIdx.x;
    const int row0 = blockIdx.x * 8;

    for (int i = tid; i < 8*FDIM; i += 128)
        fs[i] = feats[(size_t)row0*FDIM + i];
    __syncthreads();

    const int dg = tid >> 2;        // 0..31 -> dims dg*4 .. dg*4+3
    const int rp = tid & 3;         // 0..3  -> rows rp*2, rp*2+1

    float acc[4][2];
    #pragma unroll
    for (int dd = 0; dd < 4; ++dd){
        float bb = proj_b[dg*4 + dd];
        acc[dd][0] = bb; acc[dd][1] = bb;
    }

    const float4* w0 = (const float4*)(proj_w + (size_t)(dg*4+0)*FDIM);
    const float4* w1 = (const float4*)(proj_w + (size_t)(dg*4+1)*FDIM);
    const float4* w2 = (const float4*)(proj_w + (size_t)(dg*4+2)*FDIM);
    const float4* w3 = (const float4*)(proj_w + (size_t)(dg*4+3)*FDIM);
    const float4* f0 = (const float4*)(fs + (rp*2+0)*FDIM);
    const float4* f1 = (const float4*)(fs + (rp*2+1)*FDIM);

    for (int kc = 0; kc < 63; ++kc){
        float4 p0 = f0[2*kc], q0 = f0[2*kc+1];
        float4 p1 = f1[2*kc], q1 = f1[2*kc+1];
        const float4* wd[4] = {w0, w1, w2, w3};
        #pragma unroll
        for (int dd = 0; dd < 4; ++dd){
            float4 wA = wd[dd][2*kc], wB = wd[dd][2*kc+1];
            float s = acc[dd][0];
            s = fmaf(p0.x,wA.x,s); s = fmaf(p0.y,wA.y,s); s = fmaf(p0.z,wA.z,s); s = fmaf(p0.w,wA.w,s);
            s = fmaf(q0.x,wB.x,s); s = fmaf(q0.y,wB.y,s); s = fmaf(q0.z,wB.z,s); s = fmaf(q0.w,wB.w,s);
            acc[dd][0] = s;
            s = acc[dd][1];
            s = fmaf(p1.x,wA.x,s); s = fmaf(p1.y,wA.y,s); s = fmaf(p1.z,wA.z,s); s = fmaf(p1.w,wA.w,s);
            s = fmaf(q1.x,wB.x,s); s = fmaf(q1.y,wB.y,s); s = fmaf(q1.z,wB.z,s); s = fmaf(q1.w,wB.w,s);
            acc[dd][1] = s;
        }
    }
    __syncthreads();    // all fs reads done before overwrite

    #pragma unroll
    for (int dd = 0; dd < 4; ++dd){
        fs[(rp*2+0)*128 + dg*4 + dd] = acc[dd][0];
        fs[(rp*2+1)*128 + dg*4 + dd] = acc[dd][1];
    }
    __syncthreads();

    const float gl = lng[tid], bl = lnb[tid];
    #pragma unroll
    for (int g = 0; g < 8; ++g){
        float v = fs[g*128 + tid];
        float s1 = v, s2 = v*v;
        bred2(s1, s2, scr, tid);
        float m = s1 * (1.f/128.f);
        float var = fmaxf(s2 * (1.f/128.f) - m*m, 0.f);
        float y = (v - m) / sqrtf(var + 1e-5f);
        y = y*gl + bl;
        pf[(size_t)(row0 + g)*DM + tid] = fmaxf(y, 0.f);
    }
}

// ---------------------------------------------------------------------------
// Kernel F: finalize (assign from pbuf) + token pooling + 3-layer
// transformer. 128 blocks x 512 threads (R12 k-split x4). Finalize scratch
// aliased into part[] (dead until layer 0 qkv).
// ---------------------------------------------------------------------------
__global__ __launch_bounds__(512) void former_kernel(
        const float* __restrict__ pf, const float* __restrict__ pos_emb,
        const float* __restrict__ pbuf,
        const float* __restrict__ pos_enc,
        const float* __restrict__ Wqkv, const float* __restrict__ bqkv,
        const float* __restrict__ Wo,   const float* __restrict__ bo,
        const float* __restrict__ W1,   const float* __restrict__ b1,
        const float* __restrict__ W2,   const float* __restrict__ b2,
        const float* __restrict__ ln1g, const float* __restrict__ ln1b,
        const float* __restrict__ ln2g, const float* __restrict__ ln2b,
        float* __restrict__ out)
{
    __shared__ float h[5*128];
    __shared__ float qkvL[5*384];
    __shared__ float attL[100];
    __shared__ float oL[5*128];
    __shared__ float hidL[5*256];
    __shared__ float part[3*1920];    // k-split partials; finalize scratch first
    __shared__ int   asg[62];
    __shared__ float scr[4];

    const int b   = blockIdx.x;
    const int tid = threadIdx.x;
    const int d   = tid & 127;
    const int kq  = tid >> 7;         // 0..3

    // ==== inlined finalize: compute asg[] from pbuf + pos_emb[0] ====
    {
        float* Dp   = part;                 // [62*62]
        float* P    = part + 3844;          // [62*3]
        float* rsv  = part + 4030;          // [62]
        float* mdv  = part + 4092;          // [62]
        float* gs   = part + 4154;          // [15]
        float* gc   = part + 4169;          // [5]
        float* cenS = part + 4180;          // [5][3]
        int*   ordS = (int*)(part + 4200);  // [62][5]
        int*   seli = (int*)(part + 4520);  // [5]

        if (tid < 20){
            float s = 0.f;
            for (int bb2 = 0; bb2 < 128; ++bb2) s += pbuf[(size_t)bb2*20 + tid];
            if (tid < 15) gs[tid] = s; else gc[tid-15] = s;
        }
        if (tid < 62){
            #pragma unroll
            for (int j = 0; j < 3; ++j) P[tid*3 + j] = pos_emb[(size_t)tid*3 + j];
        }
        __syncthreads();
        if (tid < 62){
            float xi = P[tid*3], yi = P[tid*3+1], zi = P[tid*3+2];
            float s = 0.f;
            for (int j = 0; j < 62; ++j){
                float dx = xi - P[j*3], dy = yi - P[j*3+1], dz = zi - P[j*3+2];
                float dd = sqrtf(dx*dx + dy*dy + dz*dz);
                Dp[tid*62 + j] = dd; s += dd;
            }
            rsv[tid] = s;
        }
        __syncthreads();
        if (tid == 0){
            int bi = 0; float bv = rsv[0];
            for (int i = 1; i < 62; ++i) if (rsv[i] > bv){ bv = rsv[i]; bi = i; }
            seli[0] = bi;
            for (int i = 0; i < 62; ++i) mdv[i] = Dp[bi*62 + i];
            for (int it = 1; it < 5; ++it){
                int fi = 0; float fv = mdv[0];
                for (int i = 1; i < 62; ++i) if (mdv[i] > fv){ fv = mdv[i]; fi = i; }
                seli[it] = fi;
                for (int i = 0; i < 62; ++i) mdv[i] = fminf(mdv[i], Dp[fi*62 + i]);
            }
            float cen[5][3], avg[5][3];
            for (int t = 0; t < 5; ++t)
                for (int j = 0; j < 3; ++j) cen[t][j] = P[seli[t]*3 + j];
            for (int t = 0; t < 5; ++t){
                float c = gc[t];
                for (int j = 0; j < 3; ++j)
                    avg[t][j] = (c > 0.f) ? gs[t*3 + j] / fmaxf(c, 1.f) : 0.f;
            }
            for (int i = 0; i < 5; ++i){
                int m = 0; float bv2 = 3.4e38f;
                for (int j = 0; j < 5; ++j){
                    float dx = cen[i][0]-avg[j][0], dy = cen[i][1]-avg[j][1], dz = cen[i][2]-avg[j][2];
                    float d2 = dx*dx + dy*dy + dz*dz;
                    if (d2 < bv2){ bv2 = d2; m = j; }
                }
                for (int j = 0; j < 3; ++j) cenS[i*3 + j] = 0.8f*cen[i][j] + 0.2f*avg[m][j];
            }
        }
        __syncthreads();
        if (tid < 62){
            float dd[5];
            #pragma unroll
            for (int t = 0; t < 5; ++t){
                float dx = P[tid*3]-cenS[t*3+0], dy = P[tid*3+1]-cenS[t*3+1], dz = P[tid*3+2]-cenS[t*3+2];
                dd[t] = sqrtf(dx*dx + dy*dy + dz*dz);
            }
            bool tk[5] = {false,false,false,false,false};
            #pragma unroll
            for (int s = 0; s < 5; ++s){
                int best = -1;
                #pragma unroll
                for (int t = 0; t < 5; ++t)
                    if (!tk[t] && (best < 0 || dd[t] < dd[best])) best = t;
                tk[best] = true; ordS[tid*5 + s] = best;
            }
        }
        __syncthreads();
        if (tid == 0){
            const int sizesA[5] = {13,13,12,12,12};
            int counts[5] = {0,0,0,0,0};
            for (int i = 0; i < 62; ++i){
                int cl = ordS[i*5 + 0];
                #pragma unroll
                for (int s = 0; s < 5; ++s){
                    int t = ordS[i*5 + s];
                    if (counts[t] < sizesA[t]){ cl = t; break; }
                }
                counts[cl]++;
                asg[i] = cl;
            }
        }
        __syncthreads();
    }

    // token pooling (kq==0 threads only; same order as before)
    if (kq == 0){
        float a0=0,a1=0,a2=0,a3=0,a4=0;
        const float* pfb = pf + (size_t)b*62*DM + d;
        for (int c = 0; c < 62; ++c){
            float v = pfb[(size_t)c*DM];
            int a = asg[c];
            a0 += (a==0)?v:0.f; a1 += (a==1)?v:0.f; a2 += (a==2)?v:0.f;
            a3 += (a==3)?v:0.f; a4 += (a==4)?v:0.f;
        }
        h[0*128+d] = a0/13.f + pos_enc[0*128+d];
        h[1*128+d] = a1/13.f + pos_enc[1*128+d];
        h[2*128+d] = a2/12.f + pos_enc[2*128+d];
        h[3*128+d] = a3/12.f + pos_enc[3*128+d];
        h[4*128+d] = a4/12.f + pos_enc[4*128+d];
    }
    __syncthreads();

    for (int L = 0; L < 3; ++L){
        // ---- qkv: each kq computes a quarter of the k-range ----
        const float* Wq = Wqkv + (size_t)L*384*128;
        {
            float acc[3][5];
            #pragma unroll
            for (int rr = 0; rr < 3; ++rr){
                float bb = (kq == 0) ? bqkv[L*384 + rr*128 + d] : 0.f;
                #pragma unroll
                for (int t = 0; t < 5; ++t) acc[rr][t] = bb;
            }
            for (int kc = kq*4; kc < kq*4 + 4; ++kc){
                float hr[5][8];
                #pragma unroll
                for (int t = 0; t < 5; ++t){
                    float4 p = *(const float4*)&h[t*128 + kc*8];
                    float4 q = *(const float4*)&h[t*128 + kc*8 + 4];
                    hr[t][0]=p.x; hr[t][1]=p.y; hr[t][2]=p.z; hr[t][3]=p.w;
                    hr[t][4]=q.x; hr[t][5]=q.y; hr[t][6]=q.z; hr[t][7]=q.w;
                }
                #pragma unroll
                for (int rr = 0; rr < 3; ++rr){
                    float4 wA = *(const float4*)(Wq + ((size_t)(rr*128 + d))*128 + kc*8);
                    float4 wB = *(const float4*)(Wq + ((size_t)(rr*128 + d))*128 + kc*8 + 4);
                    #pragma unroll
                    for (int t = 0; t < 5; ++t){
                        float s = acc[rr][t];
                        s=fmaf(hr[t][0],wA.x,s); s=fmaf(hr[t][1],wA.y,s);
                        s=fmaf(hr[t][2],wA.z,s); s=fmaf(hr[t][3],wA.w,s);
                        s=fmaf(hr[t][4],wB.x,s); s=fmaf(hr[t][5],wB.y,s);
                        s=fmaf(hr[t][6],wB.z,s); s=fmaf(hr[t][7],wB.w,s);
                        acc[rr][t] = s;
                    }
                }
            }
            if (kq > 0){
                #pragma unroll
                for (int rr = 0; rr < 3; ++rr)
                    #pragma unroll
                    for (int t = 0; t < 5; ++t)
                        part[(kq-1)*1920 + t*384 + rr*128 + d] = acc[rr][t];
            }
            __syncthreads();
            if (kq == 0){
                #pragma unroll
                for (int rr = 0; rr < 3; ++rr)
                    #pragma unroll
                    for (int t = 0; t < 5; ++t){
                        int o = t*384 + rr*128 + d;
                        qkvL[o] = ((acc[rr][t] + part[o]) + part[1920 + o]) + part[3840 + o];
                    }
            }
            __syncthreads();
        }

        // ---- scores (tid<100 => kq==0) ----
        if (tid < 100){
            int hh = tid/25, rem = tid - hh*25, tq = rem/5, tk = rem - (rem/5)*5;
            const float* qq = &qkvL[tq*384 + hh*32];
            const float* kk = &qkvL[tk*384 + 128 + hh*32];
            float s = 0.f;
            #pragma unroll
            for (int j = 0; j < 32; ++j) s = fmaf(qq[j], kk[j], s);
            attL[tid] = s * 0.17677669529663687f;   // 1/sqrt(32)
        }
        __syncthreads();
        if (tid < 20){
            int hh = tid/5, tq = tid - hh*5;
            float* row = &attL[hh*25 + tq*5];
            float mx = row[0];
            #pragma unroll
            for (int j = 1; j < 5; ++j) mx = fmaxf(mx, row[j]);
            float sm = 0.f;
            #pragma unroll
            for (int j = 0; j < 5; ++j){ float e = expf(row[j]-mx); row[j] = e; sm += e; }
            float inv = 1.f/sm;
            #pragma unroll
            for (int j = 0; j < 5; ++j) row[j] *= inv;
        }
        __syncthreads();

        // ---- attention output: kq0 -> tokens {0,4}; kq1..3 -> {1,2,3} ----
        {
            int hh = d >> 5;
            int tA = kq;               // 0..3
            {
                float s = 0.f;
                #pragma unroll
                for (int tk = 0; tk < 5; ++tk)
                    s = fmaf(attL[hh*25 + tA*5 + tk], qkvL[tk*384 + 256 + d], s);
                oL[tA*128 + d] = s;
            }
            if (kq == 0){
                float s = 0.f;
                #pragma unroll
                for (int tk = 0; tk < 5; ++tk)
                    s = fmaf(attL[hh*25 + 4*5 + tk], qkvL[tk*384 + 256 + d], s);
                oL[4*128 + d] = s;
            }
        }
        __syncthreads();

        // ---- out proj (k-quarter) + residual + LN1 ----
        float val[5];
        {
            float bv = (kq == 0) ? bo[L*128 + d] : 0.f;
            #pragma unroll
            for (int t = 0; t < 5; ++t) val[t] = bv;
            const float* WoR = Wo + ((size_t)L*128 + d)*128;
            for (int kc = kq*4; kc < kq*4 + 4; ++kc){
                float orr[5][8];
                #pragma unroll
                for (int t = 0; t < 5; ++t){
                    float4 p = *(const float4*)&oL[t*128 + kc*8];
                    float4 q = *(const float4*)&oL[t*128 + kc*8 + 4];
                    orr[t][0]=p.x; orr[t][1]=p.y; orr[t][2]=p.z; orr[t][3]=p.w;
                    orr[t][4]=q.x; orr[t][5]=q.y; orr[t][6]=q.z; orr[t][7]=q.w;
                }
                float4 wA = *(const float4*)(WoR + kc*8);
                float4 wB = *(const float4*)(WoR + kc*8 + 4);
                #pragma unroll
                for (int t = 0; t < 5; ++t){
                    float s = val[t];
                    s=fmaf(orr[t][0],wA.x,s); s=fmaf(orr[t][1],wA.y,s);
                    s=fmaf(orr[t][2],wA.z,s); s=fmaf(orr[t][3],wA.w,s);
                    s=fmaf(orr[t][4],wB.x,s); s=fmaf(orr[t][5],wB.y,s);
                    s=fmaf(orr[t][6],wB.z,s); s=fmaf(orr[t][7],wB.w,s);
                    val[t] = s;
                }
            }
            if (kq > 0){
                #pragma unroll
                for (int t = 0; t < 5; ++t)
                    part[(kq-1)*1920 + t*128 + d] = val[t];
            }
            __syncthreads();
            if (kq == 0){
                #pragma unroll
                for (int t = 0; t < 5; ++t){
                    int o = t*128 + d;
                    val[t] = (((val[t] + part[o]) + part[1920 + o]) + part[3840 + o])
                             + h[t*128 + d];
                }
            }
            __syncthreads();
        }
        {
            float ng = ln1g[L*128 + d], nb = ln1b[L*128 + d];
            #pragma unroll
            for (int t = 0; t < 5; ++t){
                float s1 = val[t], s2 = val[t]*val[t];
                bred2h(s1, s2, scr, tid);
                float m = s1*(1.f/128.f);
                float var = fmaxf(s2*(1.f/128.f) - m*m, 0.f);
                float y = (val[t] - m) / sqrtf(var + 1e-5f);
                if (kq == 0) h[t*128 + d] = y*ng + nb;
            }
        }
        __syncthreads();

        // ---- FF1 (k-quarter) ----
        {
            float f1[2][5];
            #pragma unroll
            for (int rr = 0; rr < 2; ++rr){
                float bb = (kq == 0) ? b1[L*256 + rr*128 + d] : 0.f;
                #pragma unroll
                for (int t = 0; t < 5; ++t) f1[rr][t] = bb;
            }
            const float* W1b = W1 + (size_t)L*256*128;
            for (int kc = kq*4; kc < kq*4 + 4; ++kc){
                float hr[5][8];
                #pragma unroll
                for (int t = 0; t < 5; ++t){
                    float4 p = *(const float4*)&h[t*128 + kc*8];
                    float4 q = *(const float4*)&h[t*128 + kc*8 + 4];
                    hr[t][0]=p.x; hr[t][1]=p.y; hr[t][2]=p.z; hr[t][3]=p.w;
                    hr[t][4]=q.x; hr[t][5]=q.y; hr[t][6]=q.z; hr[t][7]=q.w;
                }
                #pragma unroll
                for (int rr = 0; rr < 2; ++rr){
                    float4 wA = *(const float4*)(W1b + ((size_t)(rr*128 + d))*128 + kc*8);
                    float4 wB = *(const float4*)(W1b + ((size_t)(rr*128 + d))*128 + kc*8 + 4);
                    #pragma unroll
                    for (int t = 0; t < 5; ++t){
                        float s = f1[rr][t];
                        s=fmaf(hr[t][0],wA.x,s); s=fmaf(hr[t][1],wA.y,s);
                        s=fmaf(hr[t][2],wA.z,s); s=fmaf(hr[t][3],wA.w,s);
                        s=fmaf(hr[t][4],wB.x,s); s=fmaf(hr[t][5],wB.y,s);
                        s=fmaf(hr[t][6],wB.z,s); s=fmaf(hr[t][7],wB.w,s);
                        f1[rr][t] = s;
                    }
                }
            }
            if (kq > 0){
                #pragma unroll
                for (int rr = 0; rr < 2; ++rr)
                    #pragma unroll
                    for (int t = 0; t < 5; ++t)
                        part[(kq-1)*1920 + rr*640 + t*128 + d] = f1[rr][t];
            }
            __syncthreads();
            if (kq == 0){
                #pragma unroll
                for (int rr = 0; rr < 2; ++rr)
                    #pragma unroll
                    for (int t = 0; t < 5; ++t){
                        int o = rr*640 + t*128 + d;
                        float v = ((f1[rr][t] + part[o]) + part[1920 + o]) + part[3840 + o];
                        hidL[t*256 + rr*128 + d] = fmaxf(v, 0.f);
                    }
            }
            __syncthreads();
        }

        // ---- FF2 (k-quarter) + residual + LN2 ----
        {
            float v2[5];
            float bv = (kq == 0) ? b2[L*128 + d] : 0.f;
            #pragma unroll
            for (int t = 0; t < 5; ++t) v2[t] = bv;
            const float* W2R = W2 + ((size_t)L*128 + d)*256;
            for (int kc = kq*8; kc < kq*8 + 8; ++kc){
                float hr[5][8];
                #pragma unroll
                for (int t = 0; t < 5; ++t){
                    float4 p = *(const float4*)&hidL[t*256 + kc*8];
                    float4 q = *(const float4*)&hidL[t*256 + kc*8 + 4];
                    hr[t][0]=p.x; hr[t][1]=p.y; hr[t][2]=p.z; hr[t][3]=p.w;
                    hr[t][4]=q.x; hr[t][5]=q.y; hr[t][6]=q.z; hr[t][7]=q.w;
                }
                float4 wA = *(const float4*)(W2R + kc*8);
                float4 wB = *(const float4*)(W2R + kc*8 + 4);
                #pragma unroll
                for (int t = 0; t < 5; ++t){
                    float s = v2[t];
                    s=fmaf(hr[t][0],wA.x,s); s=fmaf(hr[t][1],wA.y,s);
                    s=fmaf(hr[t][2],wA.z,s); s=fmaf(hr[t][3],wA.w,s);
                    s=fmaf(hr[t][4],wB.x,s); s=fmaf(hr[t][5],wB.y,s);
                    s=fmaf(hr[t][6],wB.z,s); s=fmaf(hr[t][7],wB.w,s);
                    v2[t] = s;
                }
            }
            if (kq > 0){
                #pragma unroll
                for (int t = 0; t < 5; ++t) part[(kq-1)*1920 + t*128 + d] = v2[t];
            }
            __syncthreads();
            if (kq == 0){
                #pragma unroll
                for (int t = 0; t < 5; ++t){
                    int o = t*128 + d;
                    v2[t] = (((v2[t] + part[o]) + part[1920 + o]) + part[3840 + o])
                            + h[t*128 + d];
                }
            }
            __syncthreads();
            float ng = ln2g[L*128 + d], nb = ln2b[L*128 + d];
            #pragma unroll
            for (int t = 0; t < 5; ++t){
                float s1 = v2[t], s2 = v2[t]*v2[t];
                bred2h(s1, s2, scr, tid);
                float m = s1*(1.f/128.f);
                float var = fmaxf(s2*(1.f/128.f) - m*m, 0.f);
                float y = (v2[t] - m) / sqrtf(var + 1e-5f);
                if (kq == 0) h[t*128 + d] = y*ng + nb;
            }
        }
        __syncthreads();
    }

    if (kq == 0){
        #pragma unroll
        for (int t = 0; t < 5; ++t)
            out[((size_t)b*5 + t)*128 + d] = h[t*128 + d];
    }
}

// ---------------------------------------------------------------------------
extern "C" void kernel_launch(void* const* d_in, const int* in_sizes, int n_in,
                              void* d_out, int out_size, void* d_ws, size_t ws_size,
                              hipStream_t stream)
{
    const float* x        = (const float*)d_in[0];
    const float* pos_emb  = (const float*)d_in[1];
    const float* proj_w   = (const float*)d_in[2];
    const float* proj_b   = (const float*)d_in[3];
    const float* proj_lng = (const float*)d_in[4];
    const float* proj_lnb = (const float*)d_in[5];
    const float* pos_enc  = (const float*)d_in[6];
    const float* Wqkv     = (const float*)d_in[7];
    const float* bqkv     = (const float*)d_in[8];
    const float* Wo       = (const float*)d_in[9];
    const float* bo       = (const float*)d_in[10];
    const float* W1       = (const float*)d_in[11];
    const float* b1       = (const float*)d_in[12];
    const float* W2       = (const float*)d_in[13];
    const float* b2       = (const float*)d_in[14];
    const float* ln1g     = (const float*)d_in[15];
    const float* ln1b     = (const float*)d_in[16];
    const float* ln2g     = (const float*)d_in[17];
    const float* ln2b     = (const float*)d_in[18];

    float* ws    = (float*)d_ws;
    float* feats = ws;                              // 128*62*504
    float* pf    = feats + (size_t)N_SIG*FDIM;      // 128*62*128
    float* gsums = pf + (size_t)N_SIG*DM;           // 15 (unused, kept for layout)
    float* gcnt  = gsums + 15;                      // 5  (unused)
    int*   assign = (int*)(gcnt + 5);               // 62 (unused)
    float* basis = (float*)(assign + 64);           // 23*50*4 = 4600
    float* pbuf  = basis + 4600;                    // 128*20 = 2560
    float* dmg   = pf;   // 128*3844 floats, aliases pf (pf written later by proj)

    float* out = (float*)d_out;

    basis_kernel<<<5, 256, 0, stream>>>(basis);
    feat_kernel<<<N_SIG, 256, 0, stream>>>(x, basis, feats);
    dist_kernel<<<256, 512, 0, stream>>>(feats, dmg);
    fps_kernel<<<128, 64, 0, stream>>>(dmg, pos_emb, pbuf);
    proj_kernel<<<992, 128, 0, stream>>>(feats, proj_w, proj_b, proj_lng, proj_lnb, pf);
    former_kernel<<<128, 512, 0, stream>>>(pf, pos_emb, pbuf, pos_enc,
        Wqkv, bqkv, Wo, bo, W1, b1, W2, b2, ln1g, ln1b, ln2g, ln2b, out);
}